// Round 5
// baseline (434.084 us; speedup 1.0000x reference)
//
#include <hip/hip_runtime.h>

#define D 64
#define BK 256     // rows per dst bucket
#define KMAX 1024  // max bucket count supported
#define PCH 6144   // edges per partition block (LDS staging = 48 KB)
#define PEPT 6     // edges per thread (1024 threads)

// ---- bf16 helpers ----
static __device__ __forceinline__ unsigned short f2bf(float f) {
    unsigned int u = __float_as_uint(f);
    unsigned int r = (u + 0x7FFFu + ((u >> 16) & 1u)) >> 16;
    return (unsigned short)r;
}
static __device__ __forceinline__ float bflo(unsigned int u) {
    return __uint_as_float(u << 16);
}
static __device__ __forceinline__ float bfhi(unsigned int u) {
    return __uint_as_float(u & 0xFFFF0000u);
}

// ---------------- init: fp32 acc (flagged rows only) + bf16 cur ----------------
__global__ void init_kernel(const float4* __restrict__ user_w,
                            const float4* __restrict__ item_w,
                            float4* __restrict__ acc,
                            ushort4* __restrict__ curb,
                            const int* __restrict__ flags,
                            int n_user4, int n_tot4) {
    int i = blockIdx.x * blockDim.x + threadIdx.x;
    if (i >= n_tot4) return;
    float4 v = (i < n_user4) ? user_w[i] : item_w[i - n_user4];
    ushort4 b;
    b.x = f2bf(v.x); b.y = f2bf(v.y); b.z = f2bf(v.z); b.w = f2bf(v.w);
    curb[i] = b;
    if (flags[i >> 4]) acc[i] = v;   // acc only read at flagged rows
}

// ---------------- flag + compact list of batch-needed rows ----------------
__global__ void flag_kernel(const int* __restrict__ bu,
                            const int* __restrict__ bp,
                            const int* __restrict__ bn,
                            int* __restrict__ flags,
                            int* __restrict__ list,
                            int* __restrict__ n_list,
                            int U_, int B_) {
    int t = blockIdx.x * blockDim.x + threadIdx.x;
    int node = -1;
    if (t < 3 * B_) {
        if (t < B_)            node = bu[t];
        else if (t < 2 * B_)   node = U_ + bp[t - B_];
        else                   node = U_ + bn[t - 2 * B_];
    }
    int old = 1;
    if (node >= 0) old = atomicExch(&flags[node], 1);
    unsigned long long m = __ballot(old == 0);
    int lane = threadIdx.x & 63;
    int myoff = __popcll(m & ((1ull << lane) - 1ull));
    int total = __popcll(m);
    int bse = 0;
    if (lane == 0 && total) bse = atomicAdd(n_list, total);
    bse = __shfl(bse, 0, 64);
    if (old == 0) list[bse + myoff] = node;
}

// ---------------- partition: LDS-staged bucket sort, coalesced writeout ----
// st entry: {src, (val_bf16<<16) | dst_off8}. Bucket k occupies st[k*S .. ).
// Staged entry packs bucket id into src high bits (needs N < 2^20, K <= 1024).
// LDS: 48 KB staging + 12 KB aux = 60 KB -> 2 blocks/CU (120/160 KB).
__global__ void __launch_bounds__(1024)
partition_kernel(const int* __restrict__ src,
                 const int* __restrict__ dst,
                 const float* __restrict__ val,
                 int* __restrict__ g_pos,
                 int2* __restrict__ st,
                 int S_, int K_, int E_) {
    __shared__ int2 stg[PCH];     // block-local bucket-sorted staging
    __shared__ int cnt[KMAX];
    __shared__ int sh[KMAX];      // inclusive scan of cnt
    __shared__ int gb[KMAX];      // global base minus local base
    int tid = threadIdx.x;
    for (int k = tid; k < K_; k += 1024) cnt[k] = 0;
    __syncthreads();
    int b0 = blockIdx.x * PCH;
    int nc = min(PCH, E_ - b0);
    int myk[PEPT], myr[PEPT], mysrc[PEPT];
    unsigned mypk[PEPT];
#pragma unroll
    for (int e = 0; e < PEPT; ++e) {
        int i = b0 + e * 1024 + tid;
        if (i < E_) {
            int d = dst[i];
            int k = d >> 8;
            myk[e] = k;
            mysrc[e] = src[i];
            mypk[e] = ((unsigned)f2bf(val[i]) << 16) | (unsigned)(d & (BK - 1));
            myr[e] = atomicAdd(&cnt[k], 1);
        } else {
            myk[e] = -1;
        }
    }
    __syncthreads();
    // inclusive scan of cnt over K_ (Hillis-Steele, 1024 threads)
    int v = (tid < K_) ? cnt[tid] : 0;
    sh[tid] = v;
    __syncthreads();
    for (int off = 1; off < KMAX; off <<= 1) {
        int t = (tid >= off) ? sh[tid - off] : 0;
        __syncthreads();
        sh[tid] += t;
        __syncthreads();
    }
    // reserve global bucket ranges; gb[k] pre-adjusted by local base
    if (tid < K_ && v) {
        int lbase = sh[tid] - v;
        gb[tid] = (tid * S_ + atomicAdd(&g_pos[tid], v)) - lbase;
    }
    __syncthreads();
    // stage into LDS at block-locally sorted position
#pragma unroll
    for (int e = 0; e < PEPT; ++e) {
        int k = myk[e];
        if (k >= 0) {
            int slot = (sh[k] - cnt[k]) + myr[e];
            stg[slot] = make_int2(mysrc[e] | (k << 20), (int)mypk[e]);
        }
    }
    __syncthreads();
    // coalesced writeout: consecutive slots -> consecutive global positions
    for (int l = tid; l < nc; l += 1024) {
        int2 ev = stg[l];
        int k = (int)((unsigned)ev.x >> 20);
        st[gb[k] + l] = make_int2(ev.x & 0xFFFFF, ev.y);
    }
}

// place: one block per bucket (1024 threads). Inline prefix over g_pos (no
// separate scan kernel), local degrees + row_span in LDS, edges cached in
// registers during histogram pass (no second st read), scatter to col_val.
__global__ void __launch_bounds__(1024)
place_kernel(const int2* __restrict__ st,
             const int* __restrict__ g_pos,
             int2* __restrict__ row_span,
             int2* __restrict__ col_val,
             int S_, int K_, int N_) {
    __shared__ int gsc[KMAX];
    __shared__ int ldeg[BK];
    __shared__ int sh[BK];
    __shared__ int lcur[BK];
    int b = blockIdx.x;
    int tid = threadIdx.x;
    int rbeg = b << 8;
    int sbeg = b * S_;
    // ---- inline exclusive prefix over g_pos to get this bucket's base ----
    int gp = (tid < K_) ? g_pos[tid] : 0;
    gsc[tid] = gp;
    if (tid < BK) ldeg[tid] = 0;
    __syncthreads();
    for (int off = 1; off < KMAX; off <<= 1) {
        int t = (tid >= off) ? gsc[tid - off] : 0;
        __syncthreads();
        gsc[tid] += t;
        __syncthreads();
    }
    int cbeg = (b > 0) ? gsc[b - 1] : 0;
    int cnt = gsc[b] - cbeg;
    // ---- histogram pass; cache edges in registers (static unroll) ----
    int2 ec0, ec1, ec2, ec3, ec4, ec5, ec6, ec7;
#define HLOAD(J, EC) { int i = tid + (J) * 1024; \
        EC = (i < cnt) ? st[sbeg + i] : make_int2(0, 0); \
        if (i < cnt) atomicAdd(&ldeg[(unsigned)EC.y & (BK - 1u)], 1); }
    HLOAD(0, ec0) HLOAD(1, ec1) HLOAD(2, ec2) HLOAD(3, ec3)
    HLOAD(4, ec4) HLOAD(5, ec5) HLOAD(6, ec6) HLOAD(7, ec7)
#undef HLOAD
    for (int i = tid + 8192; i < cnt; i += 1024)          // rare overflow
        atomicAdd(&ldeg[(unsigned)st[sbeg + i].y & (BK - 1u)], 1);
    __syncthreads();
    // ---- scan local degrees -> row spans ----
    int v = 0;
    if (tid < BK) {
        v = ldeg[tid];
        sh[tid] = v;
    }
    __syncthreads();
    for (int off = 1; off < BK; off <<= 1) {
        int t = (tid < BK && tid >= off) ? sh[tid - off] : 0;
        __syncthreads();
        if (tid < BK) sh[tid] += t;
        __syncthreads();
    }
    if (tid < BK) {
        int excl = sh[tid] - v;
        lcur[tid] = excl;
        int gi = rbeg + tid;
        if (gi < N_) row_span[gi] = make_int2(cbeg + excl, cbeg + excl + v);
    }
    __syncthreads();
    // ---- scatter from register cache ----
#define SCAT(J, EC) { int i = tid + (J) * 1024; \
        if (i < cnt) { \
            int p = cbeg + atomicAdd(&lcur[(unsigned)EC.y & (BK - 1u)], 1); \
            col_val[p] = EC; } }
    SCAT(0, ec0) SCAT(1, ec1) SCAT(2, ec2) SCAT(3, ec3)
    SCAT(4, ec4) SCAT(5, ec5) SCAT(6, ec6) SCAT(7, ec7)
#undef SCAT
    for (int i = tid + 8192; i < cnt; i += 1024) {        // rare overflow
        int2 cv = st[sbeg + i];
        int p = cbeg + atomicAdd(&lcur[(unsigned)cv.y & (BK - 1u)], 1);
        col_val[p] = cv;
    }
}

// ---------------- shared row-accumulate body (for spmm_rows) ----------------
static __device__ __forceinline__ void spmm_row_body(
        int beg, int end, int lane, int q, int lid,
        const int2* __restrict__ col_val, const uint4* __restrict__ xb,
        float& s0, float& s1, float& s2, float& s3,
        float& s4, float& s5, float& s6, float& s7) {
    for (int base = beg; base < end; base += 64) {
        int e = base + lane;
        int c = 0;
        float v = 0.f;
        if (e < end) {
            int2 cv = col_val[e];
            c = cv.x;
            v = bfhi((unsigned)cv.y);   // val in high 16 bits
        }
        int nq = (min(64, end - base) + 7) >> 3;   // 1..8 groups of 8 edges
        uint4 t0, t1, t2, t3, t4, t5, t6, t7;
        float w0, w1, w2, w3, w4, w5, w6, w7;
        { int cj = __shfl(c, q, 64);      w0 = __shfl(v, q, 64);      t0 = xb[cj * 8 + lid]; }
        if (nq > 1) { int cj = __shfl(c, 8 + q, 64);  w1 = __shfl(v, 8 + q, 64);  t1 = xb[cj * 8 + lid]; }
        if (nq > 2) { int cj = __shfl(c, 16 + q, 64); w2 = __shfl(v, 16 + q, 64); t2 = xb[cj * 8 + lid]; }
        if (nq > 3) { int cj = __shfl(c, 24 + q, 64); w3 = __shfl(v, 24 + q, 64); t3 = xb[cj * 8 + lid]; }
        if (nq > 4) { int cj = __shfl(c, 32 + q, 64); w4 = __shfl(v, 32 + q, 64); t4 = xb[cj * 8 + lid]; }
        if (nq > 5) { int cj = __shfl(c, 40 + q, 64); w5 = __shfl(v, 40 + q, 64); t5 = xb[cj * 8 + lid]; }
        if (nq > 6) { int cj = __shfl(c, 48 + q, 64); w6 = __shfl(v, 48 + q, 64); t6 = xb[cj * 8 + lid]; }
        if (nq > 7) { int cj = __shfl(c, 56 + q, 64); w7 = __shfl(v, 56 + q, 64); t7 = xb[cj * 8 + lid]; }
#define ACC8(W, T) \
        s0 += (W) * bflo((T).x); s1 += (W) * bfhi((T).x); \
        s2 += (W) * bflo((T).y); s3 += (W) * bfhi((T).y); \
        s4 += (W) * bflo((T).z); s5 += (W) * bfhi((T).z); \
        s6 += (W) * bflo((T).w); s7 += (W) * bfhi((T).w);
        { ACC8(w0, t0) }
        if (nq > 1) { ACC8(w1, t1) }
        if (nq > 2) { ACC8(w2, t2) }
        if (nq > 3) { ACC8(w3, t3) }
        if (nq > 4) { ACC8(w4, t4) }
        if (nq > 5) { ACC8(w5, t5) }
        if (nq > 6) { ACC8(w6, t6) }
        if (nq > 7) { ACC8(w7, t7) }
#undef ACC8
    }
#pragma unroll
    for (int off = 32; off >= 8; off >>= 1) {
        s0 += __shfl_xor(s0, off, 64);
        s1 += __shfl_xor(s1, off, 64);
        s2 += __shfl_xor(s2, off, 64);
        s3 += __shfl_xor(s3, off, 64);
        s4 += __shfl_xor(s4, off, 64);
        s5 += __shfl_xor(s5, off, 64);
        s6 += __shfl_xor(s6, off, 64);
        s7 += __shfl_xor(s7, off, 64);
    }
}

// ---------------- CSR gather SpMM (full layers 1-2) ----------------
// Persistent grid-stride waves; next row's row_span + first-chunk col_val are
// prefetched while the current row computes (hides the 2 serial latencies).
__global__ void __launch_bounds__(256)
spmm_csr_kernel(const int2* __restrict__ row_span,
                const int2* __restrict__ col_val,
                const uint4* __restrict__ xb,
                uint4* __restrict__ nxtb,
                float4* __restrict__ acc,
                const int* __restrict__ flags,
                int N_) {
    int lane = threadIdx.x & 63;
    int q = lane >> 3;
    int lid = lane & 7;
    int nw = (int)((gridDim.x * blockDim.x) >> 6);
    int row = (int)((blockIdx.x * blockDim.x + threadIdx.x) >> 6);
    if (row >= N_) return;
    int2 sp = row_span[row];
    int2 cv = make_int2(0, 0);
    if (sp.x + lane < sp.y) cv = col_val[sp.x + lane];
    while (true) {
        int nrow = row + nw;
        int2 spn = make_int2(0, 0);
        if (nrow < N_) spn = row_span[nrow];       // issue early
        float s0 = 0, s1 = 0, s2 = 0, s3 = 0, s4 = 0, s5 = 0, s6 = 0, s7 = 0;
        int base = sp.x;
        int end = sp.y;
        int c = cv.x;
        float v = bfhi((unsigned)cv.y);
        if (base < end) {
            while (true) {
                int nq = (min(64, end - base) + 7) >> 3;
                uint4 t0, t1, t2, t3, t4, t5, t6, t7;
                float w0, w1, w2, w3, w4, w5, w6, w7;
                { int cj = __shfl(c, q, 64);      w0 = __shfl(v, q, 64);      t0 = xb[cj * 8 + lid]; }
                if (nq > 1) { int cj = __shfl(c, 8 + q, 64);  w1 = __shfl(v, 8 + q, 64);  t1 = xb[cj * 8 + lid]; }
                if (nq > 2) { int cj = __shfl(c, 16 + q, 64); w2 = __shfl(v, 16 + q, 64); t2 = xb[cj * 8 + lid]; }
                if (nq > 3) { int cj = __shfl(c, 24 + q, 64); w3 = __shfl(v, 24 + q, 64); t3 = xb[cj * 8 + lid]; }
                if (nq > 4) { int cj = __shfl(c, 32 + q, 64); w4 = __shfl(v, 32 + q, 64); t4 = xb[cj * 8 + lid]; }
                if (nq > 5) { int cj = __shfl(c, 40 + q, 64); w5 = __shfl(v, 40 + q, 64); t5 = xb[cj * 8 + lid]; }
                if (nq > 6) { int cj = __shfl(c, 48 + q, 64); w6 = __shfl(v, 48 + q, 64); t6 = xb[cj * 8 + lid]; }
                if (nq > 7) { int cj = __shfl(c, 56 + q, 64); w7 = __shfl(v, 56 + q, 64); t7 = xb[cj * 8 + lid]; }
#define ACC8(W, T) \
                s0 += (W) * bflo((T).x); s1 += (W) * bfhi((T).x); \
                s2 += (W) * bflo((T).y); s3 += (W) * bfhi((T).y); \
                s4 += (W) * bflo((T).z); s5 += (W) * bfhi((T).z); \
                s6 += (W) * bflo((T).w); s7 += (W) * bfhi((T).w);
                { ACC8(w0, t0) }
                if (nq > 1) { ACC8(w1, t1) }
                if (nq > 2) { ACC8(w2, t2) }
                if (nq > 3) { ACC8(w3, t3) }
                if (nq > 4) { ACC8(w4, t4) }
                if (nq > 5) { ACC8(w5, t5) }
                if (nq > 6) { ACC8(w6, t6) }
                if (nq > 7) { ACC8(w7, t7) }
#undef ACC8
                base += 64;
                if (base >= end) break;
                int e = base + lane;
                int2 cvi = (e < end) ? col_val[e] : make_int2(0, 0);
                c = cvi.x;
                v = bfhi((unsigned)cvi.y);
            }
        }
        // prefetch next row's first chunk before the reduce
        int2 cvn = make_int2(0, 0);
        if (nrow < N_ && spn.x + lane < spn.y) cvn = col_val[spn.x + lane];
#pragma unroll
        for (int off = 32; off >= 8; off >>= 1) {
            s0 += __shfl_xor(s0, off, 64);
            s1 += __shfl_xor(s1, off, 64);
            s2 += __shfl_xor(s2, off, 64);
            s3 += __shfl_xor(s3, off, 64);
            s4 += __shfl_xor(s4, off, 64);
            s5 += __shfl_xor(s5, off, 64);
            s6 += __shfl_xor(s6, off, 64);
            s7 += __shfl_xor(s7, off, 64);
        }
        if (q == 0) {
            uint4 b;
            b.x = (unsigned)f2bf(s0) | ((unsigned)f2bf(s1) << 16);
            b.y = (unsigned)f2bf(s2) | ((unsigned)f2bf(s3) << 16);
            b.z = (unsigned)f2bf(s4) | ((unsigned)f2bf(s5) << 16);
            b.w = (unsigned)f2bf(s6) | ((unsigned)f2bf(s7) << 16);
            nxtb[row * 8 + lid] = b;
            if (flags[row]) {
                float4* ap = acc + row * 16 + lid * 2;
                float4 a0 = ap[0];
                a0.x += s0; a0.y += s1; a0.z += s2; a0.w += s3;
                ap[0] = a0;
                float4 a1 = ap[1];
                a1.x += s4; a1.y += s5; a1.z += s6; a1.w += s7;
                ap[1] = a1;
            }
        }
        if (nrow >= N_) break;
        row = nrow;
        sp = spn;
        cv = cvn;
    }
}

// ---------------- layer-3 SpMM over compacted flagged rows only ----------------
__global__ void spmm_rows_kernel(const int2* __restrict__ row_span,
                                 const int2* __restrict__ col_val,
                                 const uint4* __restrict__ xb,
                                 float4* __restrict__ acc,
                                 const int* __restrict__ list,
                                 const int* __restrict__ n_list) {
    int lane = threadIdx.x & 63;
    int q = lane >> 3;
    int lid = lane & 7;
    int nw = (int)((gridDim.x * blockDim.x) >> 6);
    int nl = *n_list;
    for (int w = (int)((blockIdx.x * blockDim.x + threadIdx.x) >> 6); w < nl;
         w += nw) {
        int row = list[w];
        int2 sp = row_span[row];
        float s0 = 0, s1 = 0, s2 = 0, s3 = 0, s4 = 0, s5 = 0, s6 = 0, s7 = 0;
        spmm_row_body(sp.x, sp.y, lane, q, lid, col_val, xb,
                      s0, s1, s2, s3, s4, s5, s6, s7);
        if (q == 0) {
            float4* ap = acc + row * 16 + lid * 2;
            float4 a0 = ap[0];
            a0.x += s0; a0.y += s1; a0.z += s2; a0.w += s3;
            ap[0] = a0;
            float4 a1 = ap[1];
            a1.x += s4; a1.y += s5; a1.z += s6; a1.w += s7;
            ap[1] = a1;
        }
    }
}

// ---------------- epilogue ----------------
__global__ void final_kernel(const float* __restrict__ acc,
                             const float* __restrict__ user_w,
                             const float* __restrict__ item_w,
                             const int* __restrict__ bu,
                             const int* __restrict__ bp,
                             const int* __restrict__ bn,
                             float* __restrict__ out,
                             float* __restrict__ red,
                             int U_, int B_) {
    __shared__ float pr[4];
    int w = (int)((blockIdx.x * blockDim.x + threadIdx.x) >> 6);
    int lane = threadIdx.x & 63;
    bool valid = (w < B_);
    float ps = 0.f, ns = 0.f, r = 0.f;
    if (valid) {
        int iu = bu[w], ip = bp[w], in_ = bn[w];
        const float scale = 0.25f;  // 1/(L+1)
        float u = acc[(long)iu * D + lane] * scale;
        float p = acc[(long)(U_ + ip) * D + lane] * scale;
        float g = acc[(long)(U_ + in_) * D + lane] * scale;
        ps = u * p;
        ns = u * g;
        float u0 = user_w[(long)iu * D + lane];
        float p0 = item_w[(long)ip * D + lane];
        float n0 = item_w[(long)in_ * D + lane];
        r = u0 * u0 + p0 * p0 + n0 * n0;
    }
#pragma unroll
    for (int off = 32; off; off >>= 1) {
        ps += __shfl_down(ps, off, 64);
        ns += __shfl_down(ns, off, 64);
        r  += __shfl_down(r, off, 64);
    }
    if (lane == 0) pr[threadIdx.x >> 6] = r;
    __syncthreads();
    if (threadIdx.x == 0)
        red[blockIdx.x] = pr[0] + pr[1] + pr[2] + pr[3];
    if (valid && lane == 0) {
        out[w] = ps;
        out[B_ + w] = ns;
    }
}

// single block: sum nblk partials -> out[2B]
__global__ void reduce_kernel(const float* __restrict__ red,
                              float* __restrict__ out_scalar, int nblk) {
    __shared__ float sh[256];
    float s = 0.f;
    for (int i = threadIdx.x; i < nblk; i += 256) s += red[i];
    sh[threadIdx.x] = s;
    __syncthreads();
    for (int off = 128; off; off >>= 1) {
        if (threadIdx.x < off) sh[threadIdx.x] += sh[threadIdx.x + off];
        __syncthreads();
    }
    if (threadIdx.x == 0) *out_scalar = sh[0];
}

// ---------------- launch ----------------
extern "C" void kernel_launch(void* const* d_in, const int* in_sizes, int n_in,
                              void* d_out, int out_size, void* d_ws, size_t ws_size,
                              hipStream_t stream) {
    const int*   edge_src = (const int*)d_in[0];
    const int*   edge_dst = (const int*)d_in[1];
    const float* edge_val = (const float*)d_in[2];
    const float* user_w   = (const float*)d_in[3];
    const float* item_w   = (const float*)d_in[4];
    const int*   bu       = (const int*)d_in[5];
    const int*   bp       = (const int*)d_in[6];
    const int*   bn       = (const int*)d_in[7];

    int E_ = in_sizes[0];
    int U_ = in_sizes[3] / D;
    int I_ = in_sizes[4] / D;
    int B_ = in_sizes[5];
    int N_ = U_ + I_;
    long ND = (long)N_ * D;
    int K_ = (N_ + BK - 1) >> 8;                       // 256-row dst buckets
    int S_ = ((E_ / K_) * 3 / 2 + 255) & ~255;         // 1.5x mean bucket slack

    // ---- workspace layout ----
    char* p = (char*)d_ws;
    int2* col_val  = (int2*)p;   p += (size_t)E_ * sizeof(int2);
    int2* row_span = (int2*)p;   p += (size_t)N_ * sizeof(int2);
    float* red     = (float*)p;  p += 4096 * sizeof(float);
    char* zb = p;                                   // zeroed block start
    int*  g_pos    = (int*)p;    p += KMAX * sizeof(int);
    int*  n_list   = (int*)p;    p += 256;          // padded
    int*  flags    = (int*)p;    p += (size_t)N_ * sizeof(int);
    size_t zbytes  = (size_t)(p - zb);
    int*  list     = (int*)p;    p += (size_t)3 * B_ * sizeof(int);
    p = (char*)(((uintptr_t)p + 255) & ~(uintptr_t)255);
    // overlay: staged edges (build phase) then embeddings (compute phase)
    int2* st = (int2*)p;
    float* acc = (float*)p;
    unsigned short* curb = (unsigned short*)(acc + ND);
    unsigned short* nxtb = curb + ND;
    float* out = (float*)d_out;

    int n4 = (int)(ND / 4);
    int nu4 = U_ * D / 4;

    // ---- CSR build (LDS-staged partition; scan folded into place) ----
    hipMemsetAsync(zb, 0, zbytes, stream);
    partition_kernel<<<(E_ + PCH - 1) / PCH, 1024, 0, stream>>>(
        edge_src, edge_dst, edge_val, g_pos, st, S_, K_, E_);
    place_kernel<<<K_, 1024, 0, stream>>>(st, g_pos, row_span, col_val,
                                          S_, K_, N_);

    // ---- batch-row flags + compacted list ----
    flag_kernel<<<(3 * B_ + 255) / 256, 256, 0, stream>>>(
        bu, bp, bn, flags, list, n_list, U_, B_);

    // ---- embeddings init (overwrites staged region; stream-ordered) ----
    init_kernel<<<(n4 + 255) / 256, 256, 0, stream>>>(
        (const float4*)user_w, (const float4*)item_w,
        (float4*)acc, (ushort4*)curb, flags, nu4, n4);

    // ---- propagation: layers 1-2 full (persistent waves), layer 3 batch rows
    spmm_csr_kernel<<<2048, 256, 0, stream>>>(
        row_span, col_val, (const uint4*)curb, (uint4*)nxtb, (float4*)acc,
        flags, N_);
    spmm_csr_kernel<<<2048, 256, 0, stream>>>(
        row_span, col_val, (const uint4*)nxtb, (uint4*)curb, (float4*)acc,
        flags, N_);
    spmm_rows_kernel<<<512, 256, 0, stream>>>(
        row_span, col_val, (const uint4*)curb, (float4*)acc, list, n_list);

    // ---- epilogue ----
    int nblk = (B_ * 64 + 255) / 256;
    final_kernel<<<nblk, 256, 0, stream>>>(
        acc, user_w, item_w, bu, bp, bn, out, red, U_, B_);
    reduce_kernel<<<1, 256, 0, stream>>>(red, out + 2 * B_, nblk);
}

// Round 7
// 396.609 us; speedup vs baseline: 1.0945x; 1.0945x over previous
//
#include <hip/hip_runtime.h>

#define D 64
#define BK 256     // rows per dst bucket
#define KMAX 1024  // max bucket count supported
#define PCH 6144   // edges per partition block (LDS staging = 48 KB)
#define PEPT 6     // edges per thread (1024 threads)

// ---- bf16 helpers ----
static __device__ __forceinline__ unsigned short f2bf(float f) {
    unsigned int u = __float_as_uint(f);
    unsigned int r = (u + 0x7FFFu + ((u >> 16) & 1u)) >> 16;
    return (unsigned short)r;
}
static __device__ __forceinline__ float bflo(unsigned int u) {
    return __uint_as_float(u << 16);
}
static __device__ __forceinline__ float bfhi(unsigned int u) {
    return __uint_as_float(u & 0xFFFF0000u);
}
// nontemporal 8B load of an int2-shaped pair via integer type
static __device__ __forceinline__ int2 nt_load_i2(const int2* p) {
    long long t = __builtin_nontemporal_load((const long long*)p);
    int2 r;
    r.x = (int)(unsigned)(t & 0xFFFFFFFFull);
    r.y = (int)(unsigned)((unsigned long long)t >> 32);
    return r;
}

// ---------------- init: fp32 acc (flagged rows only) + bf16 cur ----------------
__global__ void init_kernel(const float4* __restrict__ user_w,
                            const float4* __restrict__ item_w,
                            float4* __restrict__ acc,
                            ushort4* __restrict__ curb,
                            const int* __restrict__ flags,
                            int n_user4, int n_tot4) {
    int i = blockIdx.x * blockDim.x + threadIdx.x;
    if (i >= n_tot4) return;
    float4 v = (i < n_user4) ? user_w[i] : item_w[i - n_user4];
    ushort4 b;
    b.x = f2bf(v.x); b.y = f2bf(v.y); b.z = f2bf(v.z); b.w = f2bf(v.w);
    curb[i] = b;
    if (flags[i >> 4]) acc[i] = v;   // acc only read at flagged rows
}

// ---------------- flag + compact list of batch-needed rows ----------------
__global__ void flag_kernel(const int* __restrict__ bu,
                            const int* __restrict__ bp,
                            const int* __restrict__ bn,
                            int* __restrict__ flags,
                            int* __restrict__ list,
                            int* __restrict__ n_list,
                            int U_, int B_) {
    int t = blockIdx.x * blockDim.x + threadIdx.x;
    int node = -1;
    if (t < 3 * B_) {
        if (t < B_)            node = bu[t];
        else if (t < 2 * B_)   node = U_ + bp[t - B_];
        else                   node = U_ + bn[t - 2 * B_];
    }
    int old = 1;
    if (node >= 0) old = atomicExch(&flags[node], 1);
    unsigned long long m = __ballot(old == 0);
    int lane = threadIdx.x & 63;
    int myoff = __popcll(m & ((1ull << lane) - 1ull));
    int total = __popcll(m);
    int bse = 0;
    if (lane == 0 && total) bse = atomicAdd(n_list, total);
    bse = __shfl(bse, 0, 64);
    if (old == 0) list[bse + myoff] = node;
}

// ---------------- partition: LDS-staged bucket sort, coalesced writeout ----
// st entry: {src, (val_bf16<<16) | dst_off8}. Bucket k occupies st[k*S .. ).
// Staged entry packs bucket id into src high bits (needs N < 2^20, K <= 1024).
// LDS: 48 KB staging + 12 KB aux = 60 KB -> 2 blocks/CU (120/160 KB).
__global__ void __launch_bounds__(1024)
partition_kernel(const int* __restrict__ src,
                 const int* __restrict__ dst,
                 const float* __restrict__ val,
                 int* __restrict__ g_pos,
                 int2* __restrict__ st,
                 int S_, int K_, int E_) {
    __shared__ int2 stg[PCH];     // block-local bucket-sorted staging
    __shared__ int cnt[KMAX];
    __shared__ int sh[KMAX];      // inclusive scan of cnt
    __shared__ int gb[KMAX];      // global base minus local base
    int tid = threadIdx.x;
    for (int k = tid; k < K_; k += 1024) cnt[k] = 0;
    __syncthreads();
    int b0 = blockIdx.x * PCH;
    int nc = min(PCH, E_ - b0);
    int myk[PEPT], myr[PEPT], mysrc[PEPT];
    unsigned mypk[PEPT];
#pragma unroll
    for (int e = 0; e < PEPT; ++e) {
        int i = b0 + e * 1024 + tid;
        if (i < E_) {
            int d = dst[i];
            int k = d >> 8;
            myk[e] = k;
            mysrc[e] = src[i];
            mypk[e] = ((unsigned)f2bf(val[i]) << 16) | (unsigned)(d & (BK - 1));
            myr[e] = atomicAdd(&cnt[k], 1);
        } else {
            myk[e] = -1;
        }
    }
    __syncthreads();
    // inclusive scan of cnt over K_ (Hillis-Steele, 1024 threads)
    int v = (tid < K_) ? cnt[tid] : 0;
    sh[tid] = v;
    __syncthreads();
    for (int off = 1; off < KMAX; off <<= 1) {
        int t = (tid >= off) ? sh[tid - off] : 0;
        __syncthreads();
        sh[tid] += t;
        __syncthreads();
    }
    // reserve global bucket ranges; gb[k] pre-adjusted by local base
    if (tid < K_ && v) {
        int lbase = sh[tid] - v;
        gb[tid] = (tid * S_ + atomicAdd(&g_pos[tid], v)) - lbase;
    }
    __syncthreads();
    // stage into LDS at block-locally sorted position
#pragma unroll
    for (int e = 0; e < PEPT; ++e) {
        int k = myk[e];
        if (k >= 0) {
            int slot = (sh[k] - cnt[k]) + myr[e];
            stg[slot] = make_int2(mysrc[e] | (k << 20), (int)mypk[e]);
        }
    }
    __syncthreads();
    // coalesced writeout: consecutive slots -> consecutive global positions
    for (int l = tid; l < nc; l += 1024) {
        int2 ev = stg[l];
        int k = (int)((unsigned)ev.x >> 20);
        st[gb[k] + l] = make_int2(ev.x & 0xFFFFF, ev.y);
    }
}

// place: one block per bucket (1024 threads). Inline prefix over g_pos (no
// separate scan kernel), local degrees + row_span in LDS, edges cached in
// registers during histogram pass (no second st read), scatter to col_val.
__global__ void __launch_bounds__(1024)
place_kernel(const int2* __restrict__ st,
             const int* __restrict__ g_pos,
             int2* __restrict__ row_span,
             int2* __restrict__ col_val,
             int S_, int K_, int N_) {
    __shared__ int gsc[KMAX];
    __shared__ int ldeg[BK];
    __shared__ int sh[BK];
    __shared__ int lcur[BK];
    int b = blockIdx.x;
    int tid = threadIdx.x;
    int rbeg = b << 8;
    int sbeg = b * S_;
    // ---- inline exclusive prefix over g_pos to get this bucket's base ----
    int gp = (tid < K_) ? g_pos[tid] : 0;
    gsc[tid] = gp;
    if (tid < BK) ldeg[tid] = 0;
    __syncthreads();
    for (int off = 1; off < KMAX; off <<= 1) {
        int t = (tid >= off) ? gsc[tid - off] : 0;
        __syncthreads();
        gsc[tid] += t;
        __syncthreads();
    }
    int cbeg = (b > 0) ? gsc[b - 1] : 0;
    int cnt = gsc[b] - cbeg;
    // ---- histogram pass; cache edges in registers (static unroll) ----
    int2 ec0, ec1, ec2, ec3, ec4, ec5, ec6, ec7;
#define HLOAD(J, EC) { int i = tid + (J) * 1024; \
        EC = (i < cnt) ? st[sbeg + i] : make_int2(0, 0); \
        if (i < cnt) atomicAdd(&ldeg[(unsigned)EC.y & (BK - 1u)], 1); }
    HLOAD(0, ec0) HLOAD(1, ec1) HLOAD(2, ec2) HLOAD(3, ec3)
    HLOAD(4, ec4) HLOAD(5, ec5) HLOAD(6, ec6) HLOAD(7, ec7)
#undef HLOAD
    for (int i = tid + 8192; i < cnt; i += 1024)          // rare overflow
        atomicAdd(&ldeg[(unsigned)st[sbeg + i].y & (BK - 1u)], 1);
    __syncthreads();
    // ---- scan local degrees -> row spans ----
    int v = 0;
    if (tid < BK) {
        v = ldeg[tid];
        sh[tid] = v;
    }
    __syncthreads();
    for (int off = 1; off < BK; off <<= 1) {
        int t = (tid < BK && tid >= off) ? sh[tid - off] : 0;
        __syncthreads();
        if (tid < BK) sh[tid] += t;
        __syncthreads();
    }
    if (tid < BK) {
        int excl = sh[tid] - v;
        lcur[tid] = excl;
        int gi = rbeg + tid;
        if (gi < N_) row_span[gi] = make_int2(cbeg + excl, cbeg + excl + v);
    }
    __syncthreads();
    // ---- scatter from register cache ----
#define SCAT(J, EC) { int i = tid + (J) * 1024; \
        if (i < cnt) { \
            int p = cbeg + atomicAdd(&lcur[(unsigned)EC.y & (BK - 1u)], 1); \
            col_val[p] = EC; } }
    SCAT(0, ec0) SCAT(1, ec1) SCAT(2, ec2) SCAT(3, ec3)
    SCAT(4, ec4) SCAT(5, ec5) SCAT(6, ec6) SCAT(7, ec7)
#undef SCAT
    for (int i = tid + 8192; i < cnt; i += 1024) {        // rare overflow
        int2 cv = st[sbeg + i];
        int p = cbeg + atomicAdd(&lcur[(unsigned)cv.y & (BK - 1u)], 1);
        col_val[p] = cv;
    }
}

// ---------------- shared row-accumulate body ----------------
// col_val is streamed exactly once per layer: nontemporal loads keep L2 for
// the reused x rows (the only data with reuse). xb loads stay cached.
static __device__ __forceinline__ void spmm_row_body(
        int beg, int end, int lane, int q, int lid,
        const int2* __restrict__ col_val, const uint4* __restrict__ xb,
        float& s0, float& s1, float& s2, float& s3,
        float& s4, float& s5, float& s6, float& s7) {
    for (int base = beg; base < end; base += 64) {
        int e = base + lane;
        int c = 0;
        float v = 0.f;
        if (e < end) {
            int2 cv = nt_load_i2(&col_val[e]);
            c = cv.x;
            v = bfhi((unsigned)cv.y);   // val in high 16 bits
        }
        int nq = (min(64, end - base) + 7) >> 3;   // 1..8 groups of 8 edges
        uint4 t0, t1, t2, t3, t4, t5, t6, t7;
        float w0, w1, w2, w3, w4, w5, w6, w7;
        { int cj = __shfl(c, q, 64);      w0 = __shfl(v, q, 64);      t0 = xb[cj * 8 + lid]; }
        if (nq > 1) { int cj = __shfl(c, 8 + q, 64);  w1 = __shfl(v, 8 + q, 64);  t1 = xb[cj * 8 + lid]; }
        if (nq > 2) { int cj = __shfl(c, 16 + q, 64); w2 = __shfl(v, 16 + q, 64); t2 = xb[cj * 8 + lid]; }
        if (nq > 3) { int cj = __shfl(c, 24 + q, 64); w3 = __shfl(v, 24 + q, 64); t3 = xb[cj * 8 + lid]; }
        if (nq > 4) { int cj = __shfl(c, 32 + q, 64); w4 = __shfl(v, 32 + q, 64); t4 = xb[cj * 8 + lid]; }
        if (nq > 5) { int cj = __shfl(c, 40 + q, 64); w5 = __shfl(v, 40 + q, 64); t5 = xb[cj * 8 + lid]; }
        if (nq > 6) { int cj = __shfl(c, 48 + q, 64); w6 = __shfl(v, 48 + q, 64); t6 = xb[cj * 8 + lid]; }
        if (nq > 7) { int cj = __shfl(c, 56 + q, 64); w7 = __shfl(v, 56 + q, 64); t7 = xb[cj * 8 + lid]; }
#define ACC8(W, T) \
        s0 += (W) * bflo((T).x); s1 += (W) * bfhi((T).x); \
        s2 += (W) * bflo((T).y); s3 += (W) * bfhi((T).y); \
        s4 += (W) * bflo((T).z); s5 += (W) * bfhi((T).z); \
        s6 += (W) * bflo((T).w); s7 += (W) * bfhi((T).w);
        { ACC8(w0, t0) }
        if (nq > 1) { ACC8(w1, t1) }
        if (nq > 2) { ACC8(w2, t2) }
        if (nq > 3) { ACC8(w3, t3) }
        if (nq > 4) { ACC8(w4, t4) }
        if (nq > 5) { ACC8(w5, t5) }
        if (nq > 6) { ACC8(w6, t6) }
        if (nq > 7) { ACC8(w7, t7) }
#undef ACC8
    }
#pragma unroll
    for (int off = 32; off >= 8; off >>= 1) {
        s0 += __shfl_xor(s0, off, 64);
        s1 += __shfl_xor(s1, off, 64);
        s2 += __shfl_xor(s2, off, 64);
        s3 += __shfl_xor(s3, off, 64);
        s4 += __shfl_xor(s4, off, 64);
        s5 += __shfl_xor(s5, off, 64);
        s6 += __shfl_xor(s6, off, 64);
        s7 += __shfl_xor(s7, off, 64);
    }
}

// ---------------- CSR gather SpMM (full layers 1-2) ----------------
// One row per wave, short blocks (scheduler tail-fill beats persistent waves
// here: R5 persistent-wave A/B regressed 82.6 -> 100.1 us).
__global__ void spmm_csr_kernel(const int2* __restrict__ row_span,
                                const int2* __restrict__ col_val,
                                const uint4* __restrict__ xb,
                                uint4* __restrict__ nxtb,
                                float4* __restrict__ acc,
                                const int* __restrict__ flags,
                                int N_) {
    int row = (int)((blockIdx.x * blockDim.x + threadIdx.x) >> 6);
    int lane = threadIdx.x & 63;
    if (row >= N_) return;
    int q = lane >> 3;
    int lid = lane & 7;
    int2 sp = nt_load_i2(&row_span[row]);
    float s0 = 0, s1 = 0, s2 = 0, s3 = 0, s4 = 0, s5 = 0, s6 = 0, s7 = 0;
    spmm_row_body(sp.x, sp.y, lane, q, lid, col_val, xb,
                  s0, s1, s2, s3, s4, s5, s6, s7);
    if (q == 0) {
        uint4 b;
        b.x = (unsigned)f2bf(s0) | ((unsigned)f2bf(s1) << 16);
        b.y = (unsigned)f2bf(s2) | ((unsigned)f2bf(s3) << 16);
        b.z = (unsigned)f2bf(s4) | ((unsigned)f2bf(s5) << 16);
        b.w = (unsigned)f2bf(s6) | ((unsigned)f2bf(s7) << 16);
        nxtb[row * 8 + lid] = b;
        if (flags[row]) {
            float4* ap = acc + row * 16 + lid * 2;
            float4 a0 = ap[0];
            a0.x += s0; a0.y += s1; a0.z += s2; a0.w += s3;
            ap[0] = a0;
            float4 a1 = ap[1];
            a1.x += s4; a1.y += s5; a1.z += s6; a1.w += s7;
            ap[1] = a1;
        }
    }
}

// ---------------- layer-3 SpMM over compacted flagged rows only ----------------
__global__ void spmm_rows_kernel(const int2* __restrict__ row_span,
                                 const int2* __restrict__ col_val,
                                 const uint4* __restrict__ xb,
                                 float4* __restrict__ acc,
                                 const int* __restrict__ list,
                                 const int* __restrict__ n_list) {
    int w = (int)((blockIdx.x * blockDim.x + threadIdx.x) >> 6);
    if (w >= *n_list) return;
    int row = list[w];
    int lane = threadIdx.x & 63;
    int q = lane >> 3;
    int lid = lane & 7;
    int2 sp = row_span[row];
    float s0 = 0, s1 = 0, s2 = 0, s3 = 0, s4 = 0, s5 = 0, s6 = 0, s7 = 0;
    spmm_row_body(sp.x, sp.y, lane, q, lid, col_val, xb,
                  s0, s1, s2, s3, s4, s5, s6, s7);
    if (q == 0) {
        float4* ap = acc + row * 16 + lid * 2;
        float4 a0 = ap[0];
        a0.x += s0; a0.y += s1; a0.z += s2; a0.w += s3;
        ap[0] = a0;
        float4 a1 = ap[1];
        a1.x += s4; a1.y += s5; a1.z += s6; a1.w += s7;
        ap[1] = a1;
    }
}

// ---------------- epilogue ----------------
__global__ void final_kernel(const float* __restrict__ acc,
                             const float* __restrict__ user_w,
                             const float* __restrict__ item_w,
                             const int* __restrict__ bu,
                             const int* __restrict__ bp,
                             const int* __restrict__ bn,
                             float* __restrict__ out,
                             float* __restrict__ red,
                             int U_, int B_) {
    __shared__ float pr[4];
    int w = (int)((blockIdx.x * blockDim.x + threadIdx.x) >> 6);
    int lane = threadIdx.x & 63;
    bool valid = (w < B_);
    float ps = 0.f, ns = 0.f, r = 0.f;
    if (valid) {
        int iu = bu[w], ip = bp[w], in_ = bn[w];
        const float scale = 0.25f;  // 1/(L+1)
        float u = acc[(long)iu * D + lane] * scale;
        float p = acc[(long)(U_ + ip) * D + lane] * scale;
        float g = acc[(long)(U_ + in_) * D + lane] * scale;
        ps = u * p;
        ns = u * g;
        float u0 = user_w[(long)iu * D + lane];
        float p0 = item_w[(long)ip * D + lane];
        float n0 = item_w[(long)in_ * D + lane];
        r = u0 * u0 + p0 * p0 + n0 * n0;
    }
#pragma unroll
    for (int off = 32; off; off >>= 1) {
        ps += __shfl_down(ps, off, 64);
        ns += __shfl_down(ns, off, 64);
        r  += __shfl_down(r, off, 64);
    }
    if (lane == 0) pr[threadIdx.x >> 6] = r;
    __syncthreads();
    if (threadIdx.x == 0)
        red[blockIdx.x] = pr[0] + pr[1] + pr[2] + pr[3];
    if (valid && lane == 0) {
        out[w] = ps;
        out[B_ + w] = ns;
    }
}

// single block: sum nblk partials -> out[2B]
__global__ void reduce_kernel(const float* __restrict__ red,
                              float* __restrict__ out_scalar, int nblk) {
    __shared__ float sh[256];
    float s = 0.f;
    for (int i = threadIdx.x; i < nblk; i += 256) s += red[i];
    sh[threadIdx.x] = s;
    __syncthreads();
    for (int off = 128; off; off >>= 1) {
        if (threadIdx.x < off) sh[threadIdx.x] += sh[threadIdx.x + off];
        __syncthreads();
    }
    if (threadIdx.x == 0) *out_scalar = sh[0];
}

// ---------------- launch ----------------
extern "C" void kernel_launch(void* const* d_in, const int* in_sizes, int n_in,
                              void* d_out, int out_size, void* d_ws, size_t ws_size,
                              hipStream_t stream) {
    const int*   edge_src = (const int*)d_in[0];
    const int*   edge_dst = (const int*)d_in[1];
    const float* edge_val = (const float*)d_in[2];
    const float* user_w   = (const float*)d_in[3];
    const float* item_w   = (const float*)d_in[4];
    const int*   bu       = (const int*)d_in[5];
    const int*   bp       = (const int*)d_in[6];
    const int*   bn       = (const int*)d_in[7];

    int E_ = in_sizes[0];
    int U_ = in_sizes[3] / D;
    int I_ = in_sizes[4] / D;
    int B_ = in_sizes[5];
    int N_ = U_ + I_;
    long ND = (long)N_ * D;
    int K_ = (N_ + BK - 1) >> 8;                       // 256-row dst buckets
    int S_ = ((E_ / K_) * 3 / 2 + 255) & ~255;         // 1.5x mean bucket slack

    // ---- workspace layout ----
    char* p = (char*)d_ws;
    int2* col_val  = (int2*)p;   p += (size_t)E_ * sizeof(int2);
    int2* row_span = (int2*)p;   p += (size_t)N_ * sizeof(int2);
    float* red     = (float*)p;  p += 4096 * sizeof(float);
    char* zb = p;                                   // zeroed block start
    int*  g_pos    = (int*)p;    p += KMAX * sizeof(int);
    int*  n_list   = (int*)p;    p += 256;          // padded
    int*  flags    = (int*)p;    p += (size_t)N_ * sizeof(int);
    size_t zbytes  = (size_t)(p - zb);
    int*  list     = (int*)p;    p += (size_t)3 * B_ * sizeof(int);
    p = (char*)(((uintptr_t)p + 255) & ~(uintptr_t)255);
    // overlay: staged edges (build phase) then embeddings (compute phase)
    int2* st = (int2*)p;
    float* acc = (float*)p;
    unsigned short* curb = (unsigned short*)(acc + ND);
    unsigned short* nxtb = curb + ND;
    float* out = (float*)d_out;

    int n4 = (int)(ND / 4);
    int nu4 = U_ * D / 4;

    // ---- CSR build (LDS-staged partition; scan folded into place) ----
    hipMemsetAsync(zb, 0, zbytes, stream);
    partition_kernel<<<(E_ + PCH - 1) / PCH, 1024, 0, stream>>>(
        edge_src, edge_dst, edge_val, g_pos, st, S_, K_, E_);
    place_kernel<<<K_, 1024, 0, stream>>>(st, g_pos, row_span, col_val,
                                          S_, K_, N_);

    // ---- batch-row flags + compacted list ----
    flag_kernel<<<(3 * B_ + 255) / 256, 256, 0, stream>>>(
        bu, bp, bn, flags, list, n_list, U_, B_);

    // ---- embeddings init (overwrites staged region; stream-ordered) ----
    init_kernel<<<(n4 + 255) / 256, 256, 0, stream>>>(
        (const float4*)user_w, (const float4*)item_w,
        (float4*)acc, (ushort4*)curb, flags, nu4, n4);

    // ---- propagation: layers 1-2 full, layer 3 only batch rows ----
    spmm_csr_kernel<<<(N_ + 3) / 4, 256, 0, stream>>>(
        row_span, col_val, (const uint4*)curb, (uint4*)nxtb, (float4*)acc,
        flags, N_);
    spmm_csr_kernel<<<(N_ + 3) / 4, 256, 0, stream>>>(
        row_span, col_val, (const uint4*)nxtb, (uint4*)curb, (float4*)acc,
        flags, N_);
    spmm_rows_kernel<<<(3 * B_ + 3) / 4, 256, 0, stream>>>(
        row_span, col_val, (const uint4*)curb, (float4*)acc, list, n_list);

    // ---- epilogue ----
    int nblk = (B_ * 64 + 255) / 256;
    final_kernel<<<nblk, 256, 0, stream>>>(
        acc, user_w, item_w, bu, bp, bn, out, red, U_, B_);
    reduce_kernel<<<1, 256, 0, stream>>>(red, out + 2 * B_, nblk);
}